// Round 7
// baseline (180.600 us; speedup 1.0000x reference)
//
#include <hip/hip_runtime.h>

// GaussianRecuModel: B=512 batches, T=8192-step affine recurrence on 2-state x.
//   x_{t+1} = Mt x_t + bt,  Mt = I + dt*A - dt*(xic_t C),  bt = xic_t dy_t
//   out_t   = dt * C x_t   (state BEFORE update)
//
// R4: wave-coalesced float4 global access; XOR-swizzled per-wave LDS slice
//     transposes coalesced order <-> 8-contiguous-steps-per-thread order.
// R5/R6: 32 KiB/block. LDS is NOT the residency limiter (~1 block/CU even at
//     32 KiB). R7/R8/R9: compiler hard-caps 1024-thread blocks at 64 VGPR
//     (launch_bounds(NT,4) AND waves_per_eu(4,4) both ignored for the reg
//     budget); any register prefetch of batch-1 inputs spills to scratch
//     (WRITE_SIZE 32->49->79 MB).
// R10: zero-register xic pipeline. Batch-1 xic (8 KiB/wave, ALL 8 columns)
//     is staged via global_load_lds into a 128 KiB stage whose GLOBAL source
//     addresses are pre-swizzled so the linear LDS layout equals the
//     swizzled own-order layout (global_load_lds writes base+lane*16 only).
//     Batch-1 reads a[] DIRECTLY from the stage (conflict-free b128,
//     addr = lane*8 + (s^(lane&7))) -- no t1 registers, no batch-1 xic
//     transpose. Only dy-1 (u1, 16 regs) is register-prefetched, at the
//     post-replay valley. LDS = 32 KiB work + 128 KiB stage = 160 KiB exact.

#define B_   512
#define T_   8192
#define LPT  8                  // steps per thread
#define NT   1024               // threads per block (16 waves)
#define NB   2                  // batches per block
static_assert(NT * LPT == T_, "one block covers one batch");

#define SLICE_F4 128            // 2 KiB work slice per wave
#define STAGE_F4 512            // 8 KiB stage per wave (full batch-1 xic)

struct Aff { float m00, m01, m10, m11, v0, v1; };

__device__ __forceinline__ Aff aff_compose(const Aff& L, const Aff& E) {
    Aff r;
    r.m00 = L.m00*E.m00 + L.m01*E.m10;
    r.m01 = L.m00*E.m01 + L.m01*E.m11;
    r.m10 = L.m10*E.m00 + L.m11*E.m10;
    r.m11 = L.m10*E.m01 + L.m11*E.m11;
    r.v0  = L.m00*E.v0  + L.m01*E.v1 + L.v0;
    r.v1  = L.m10*E.v0  + L.m11*E.v1 + L.v1;
    return r;
}

__device__ __forceinline__ Aff aff_identity() {
    Aff r; r.m00 = 1.f; r.m01 = 0.f; r.m10 = 0.f; r.m11 = 1.f; r.v0 = 0.f; r.v1 = 0.f;
    return r;
}

// Direct global->LDS copy, 16B per lane, no destination registers.
// LDS dest = wave-uniform base + lane*16 (hardware-fixed); global src per-lane.
__device__ __forceinline__ void glds16(const float4* g, float4* l) {
    __builtin_amdgcn_global_load_lds(
        (const __attribute__((address_space(1))) void*)g,
        (__attribute__((address_space(3))) void*)l,
        16, 0, 0);
}

// STEP_MAP uses locals a[], d[] and the cd/i constants of the enclosing scope.
#define STEP_MAP(i, S)                                                  \
    {                                                                   \
        const float4 x4 = a[i];                                         \
        const float dyx = ((i)&1) ? d[(i)>>1].z : d[(i)>>1].x;          \
        const float dyy = ((i)&1) ? d[(i)>>1].w : d[(i)>>1].y;          \
        (S).m00 = i00 - (x4.x*cd00 + x4.y*cd10);                        \
        (S).m01 = i01 - (x4.x*cd01 + x4.y*cd11);                        \
        (S).m10 = i10 - (x4.z*cd00 + x4.w*cd10);                        \
        (S).m11 = i11 - (x4.z*cd01 + x4.w*cd11);                        \
        (S).v0  = x4.x*dyx + x4.y*dyy;                                  \
        (S).v1  = x4.z*dyx + x4.w*dyy;                                  \
    }

// dy transpose: coalesced u[4] -> own-order d[4], two owner-rounds through
// the 2 KiB work slice. o = f>>2, rel = o&31, slot = f&3; XOR swizzle.
// Same-wave DS ordering makes slice reuse safe without barriers.
__device__ __forceinline__ void dy_transpose(
    const float4 (&u)[4], float4 (&d)[4], float4* __restrict__ slice,
    const int lane)
{
    #pragma unroll
    for (int r = 0; r < 2; ++r) {
        #pragma unroll
        for (int jj = 0; jj < 2; ++jj) {
            int j = 2*r + jj;
            int f = j*64 + lane;
            int rel = (f >> 2) & 31;
            slice[rel*4 + ((lane & 3) ^ (rel & 3))] = u[j];
        }
        if ((lane >> 5) == r) {
            int rel = lane & 31;
            #pragma unroll
            for (int s = 0; s < 4; ++s)
                d[s] = slice[rel*4 + (s ^ (rel & 3))];
        }
    }
}

// Compose -> wave scan -> block scan -> replay -> coalesced store.
// If PREFETCH: at the post-replay register valley (a[]/d[] dead), issues the
// next batch's dy loads into u_next (the only cross-batch register state).
template<bool PREFETCH>
__device__ __forceinline__ void scan_and_emit(
    float4 (&a)[LPT], float4 (&d)[4],
    float4* __restrict__ slice, float4* __restrict__ ldsw,
    const int lane, const int wave,
    const float cd00, const float cd01, const float cd10, const float cd11,
    const float i00, const float i01, const float i10, const float i11,
    float4* __restrict__ ow,
    const float4* __restrict__ dw_next, float4 (&u_next)[4])
{
    // ---- thread-local compose: P = T7 o ... o T0 ----
    Aff P;
    STEP_MAP(0, P);
    #pragma unroll
    for (int i = 1; i < LPT; ++i) { Aff s; STEP_MAP(i, s); P = aff_compose(s, P); }

    // ---- wave Kogge-Stone inclusive scan (64 lanes) ----
    Aff S = P;
    #pragma unroll
    for (int sh = 1; sh < 64; sh <<= 1) {
        Aff q;
        q.m00 = __shfl_up(S.m00, sh); q.m01 = __shfl_up(S.m01, sh);
        q.m10 = __shfl_up(S.m10, sh); q.m11 = __shfl_up(S.m11, sh);
        q.v0  = __shfl_up(S.v0,  sh); q.v1  = __shfl_up(S.v1,  sh);
        if (lane >= sh) S = aff_compose(S, q);
    }

    // ---- wave totals -> own slice header (slice free: a,d in regs) ----
    if (lane == 63) {
        float* h = (float*)slice;
        h[0] = S.m00; h[1] = S.m01; h[2] = S.m10; h[3] = S.m11;
        h[4] = S.v0;  h[5] = S.v1;
    }
    __syncthreads();   // also the natural drain point for in-flight stages

    // ---- wave-exclusive prefix (serial over earlier waves' headers) ----
    Aff Ew = aff_identity();
    for (int w = 0; w < wave; ++w) {
        const float* h = (const float*)(ldsw + w * SLICE_F4);
        Aff t2;
        t2.m00 = h[0]; t2.m01 = h[1]; t2.m10 = h[2]; t2.m11 = h[3];
        t2.v0  = h[4]; t2.v1  = h[5];
        Ew = aff_compose(t2, Ew);
    }
    __syncthreads();   // headers consumed; slices reusable for out staging

    // ---- lane-exclusive prefix within wave ----
    Aff El;
    El.m00 = __shfl_up(S.m00, 1); El.m01 = __shfl_up(S.m01, 1);
    El.m10 = __shfl_up(S.m10, 1); El.m11 = __shfl_up(S.m11, 1);
    El.v0  = __shfl_up(S.v0,  1); El.v1  = __shfl_up(S.v1,  1);
    if (lane == 0) El = aff_identity();

    Aff E = aff_compose(El, Ew);
    float x0 = E.m00 + E.v0;
    float x1 = E.m10 + E.v1;

    // ---- replay from registers ----
    float4 o4[4];
    #pragma unroll
    for (int i = 0; i < LPT; ++i) {
        float oxx = cd00*x0 + cd01*x1;
        float oyy = cd10*x0 + cd11*x1;
        if (i & 1) { o4[i>>1].z = oxx; o4[i>>1].w = oyy; }
        else       { o4[i>>1].x = oxx; o4[i>>1].y = oyy; }
        Aff s; STEP_MAP(i, s);
        float nx0 = s.m00*x0 + s.m01*x1 + s.v0;
        float nx1 = s.m10*x0 + s.m11*x1 + s.v1;
        x0 = nx0; x1 = nx1;
    }

    // ---- valley prefetch: a[]/d[] just died; only +16 regs, covered by the
    // out-transpose below and the next batch's stage reads.
    if constexpr (PREFETCH) {
        #pragma unroll
        for (int j = 0; j < 4; ++j) u_next[j] = dw_next[j*64 + lane];
    }

    // ---- out transpose: own-order -> coalesced stores, two rounds ----
    #pragma unroll
    for (int r = 0; r < 2; ++r) {
        if ((lane >> 5) == r) {
            int rel = lane & 31;
            #pragma unroll
            for (int s = 0; s < 4; ++s)
                slice[rel*4 + (s ^ (rel & 3))] = o4[s];
        }
        #pragma unroll
        for (int jj = 0; jj < 2; ++jj) {
            int j = 2*r + jj;
            int f = j*64 + lane;
            int rel = (f >> 2) & 31;
            ow[f] = slice[rel*4 + ((lane & 3) ^ (rel & 3))];
        }
    }
}

__global__ __launch_bounds__(NT, 4) void grm_fused(
    const float* __restrict__ xic, const float* __restrict__ dy,
    const float* __restrict__ Aptr, const float* __restrict__ Cptr,
    float4* __restrict__ out4)
{
    // work : 16 waves x 2 KiB transposing slices (barrier-guarded headers).
    // stage: 16 waves x 8 KiB batch-1 xic, swizzled-at-the-source so the
    //        linear global_load_lds layout IS the own-order swizzled layout.
    // Total 163840 B (160 KiB exact; R8 proved this block size launches).
    __shared__ float4 work [16 * SLICE_F4];
    __shared__ float4 stage[16 * STAGE_F4];

    const int tid  = threadIdx.x;
    const int lane = tid & 63;
    const int wave = tid >> 6;

    float4* slice = work  + wave * SLICE_F4;
    float4* stw   = stage + wave * STAGE_F4;

    const float DT = 1e-3f;
    const float cd00 = Cptr[0]*DT, cd01 = Cptr[1]*DT;
    const float cd10 = Cptr[2]*DT, cd11 = Cptr[3]*DT;
    const float i00 = 1.0f + Aptr[0]*DT, i01 = Aptr[1]*DT;
    const float i10 = Aptr[2]*DT,        i11 = 1.0f + Aptr[3]*DT;

    // global bases in float4 units; wave covers 512 steps of each batch
    const int b0     = blockIdx.x * NB;
    const int wbase0 = b0 * T_ + wave * 512;                // batch 0 step idx
    const int wbase1 = wbase0 + T_;                          // batch 1 step idx
    const float4* xw0 = (const float4*)xic + wbase0;
    const float4* dw0 = (const float4*)dy  + (wbase0 >> 1);
    float4*       ow0 = out4 + (wbase0 >> 1);
    const float4* xw1 = (const float4*)xic + wbase1;
    const float4* dw1 = (const float4*)dy  + (wbase1 >> 1);
    float4*       ow1 = out4 + (wbase1 >> 1);

    // ---- batch-0 register loads first (service priority), then batch-1 xic
    // stage with PRE-SWIZZLED sources (zero dest registers). For LDS slot
    // L = j*64+lane the source f4 index is
    //   f = j*64 + (lane&~7) + ((lane&7) ^ (lane>>3))
    // so that stage[o*8 + (s^(o&7))] = xic f4 (o*8+s): the own-order read
    // below is bank-conflict-free and needs no transpose. Each 8-lane group
    // reads a permutation of 8 consecutive float4 -> fully coalesced.
    float4 t0[8], u0[4], u1[4];
    #pragma unroll
    for (int j = 0; j < 8; ++j) t0[j] = xw0[j*64 + lane];
    #pragma unroll
    for (int j = 0; j < 4; ++j) u0[j] = dw0[j*64 + lane];
    const int swz = (lane & ~7) | ((lane & 7) ^ (lane >> 3));
    #pragma unroll
    for (int j = 0; j < 8; ++j) glds16(xw1 + j*64 + swz, stw + j*64);

    // ---- batch 0 front: xic transpose, four owner-rounds through the work
    // slice. Round r covers f in [128r,128r+128); owner o=f>>3, rel=o&15,
    // slot=lane&7, swizzled addr = rel*8 + (slot^(rel&7)). Writes conflict-
    // free; reads 2-way max (free). Same-wave ordering -> no barriers.
    float4 a0[LPT];
    #pragma unroll
    for (int r = 0; r < 4; ++r) {
        #pragma unroll
        for (int jj = 0; jj < 2; ++jj) {
            int j = 2*r + jj;
            int f = j*64 + lane;
            int rel = (f >> 3) & 15;
            slice[rel*8 + ((lane & 7) ^ (rel & 7))] = t0[j];
        }
        if ((lane >> 4) == r) {
            int rel = lane & 15;
            #pragma unroll
            for (int s = 0; s < LPT; ++s)
                a0[s] = slice[rel*8 + (s ^ (rel & 7))];
        }
    }
    float4 d0[4];
    dy_transpose(u0, d0, slice, lane);

    // batch 0: scan/emit; prefetches u1 (dy-1) at the post-replay valley.
    scan_and_emit<true>(a0, d0, slice, work, lane, wave,
                        cd00, cd01, cd10, cd11, i00, i01, i10, i11,
                        ow0, dw1, u1);

    // ---- batch 1 front: a[] straight from the swizzled stage (no t1 regs,
    // no transpose). addr = lane*8 + (s^(lane&7)): 8 lanes per bank-quad =
    // the ds_read_b128 minimum, conflict-free. Arrival was guaranteed by
    // batch-0's first __syncthreads (vmcnt drain).
    float4 a1[LPT];
    #pragma unroll
    for (int s = 0; s < LPT; ++s)
        a1[s] = stw[lane*8 + (s ^ (lane & 7))];
    float4 d1[4];
    dy_transpose(u1, d1, slice, lane);

    scan_and_emit<false>(a1, d1, slice, work, lane, wave,
                         cd00, cd01, cd10, cd11, i00, i01, i10, i11,
                         ow1, dw1, u1);
}

#undef STEP_MAP

extern "C" void kernel_launch(void* const* d_in, const int* in_sizes, int n_in,
                              void* d_out, int out_size, void* d_ws, size_t ws_size,
                              hipStream_t stream) {
    const float* xic  = (const float*)d_in[0];   // [B,T,2,2]
    const float* dy   = (const float*)d_in[1];   // [B,T,2]
    const float* Aptr = (const float*)d_in[2];   // [2,2]
    const float* Cptr = (const float*)d_in[3];   // [2,2]
    float4* out = (float4*)d_out;                // [B,T,2]

    grm_fused<<<B_ / NB, NT, 0, stream>>>(xic, dy, Aptr, Cptr, out);
}

// Round 8
// 177.060 us; speedup vs baseline: 1.0200x; 1.0200x over previous
//
#include <hip/hip_runtime.h>

// GaussianRecuModel: B=512 batches, T=8192-step affine recurrence on 2-state x.
//   x_{t+1} = Mt x_t + bt,  Mt = I + dt*A - dt*(xic_t C),  bt = xic_t dy_t
//   out_t   = dt * C x_t   (state BEFORE update)
//
// R4:    wave-coalesced float4 global access; XOR-swizzled per-wave LDS slice
//        transposes coalesced order <-> 8-contiguous-steps-per-thread order.
// R5/R6: LDS size is NOT the 1024-thr residency limiter (1 block/CU even at
//        32 KiB). R7-R10: compiler pins 1024-thr blocks at 64 VGPR (all
//        override attempts ignored); every pipeline variant spilled
//        (WRITE_SIZE 32->49->79->97 MB). 1024-thr monolith = dead end.
// R11:   512-thread blocks (8 waves), one batch per block, TWO sequential
//        chunks of 4096 steps chained through a 2-float state carry. Per-wave
//        flow is byte-identical to the passing 52-VGPR R6 kernel. A 512-thr
//        block (16 KiB LDS, <=64 VGPR) allows 2-4 co-resident blocks per CU:
//        block A's global-load phase overlaps block B's scan/VALU phase --
//        the cross-phase overlap R7-R10 failed to buy with registers, now
//        provided by the hardware scheduler. No prefetch registers at all.

#define B_   512
#define T_   8192
#define LPT  8                   // steps per thread per chunk
#define NT   512                 // threads per block (8 waves)
#define NW   (NT / 64)           // waves per block
#define NCH  2                   // chunks per batch
static_assert(NT * LPT * NCH == T_, "chunks cover one batch");

#define SLICE_F4 128             // 2 KiB work slice per wave

struct Aff { float m00, m01, m10, m11, v0, v1; };

__device__ __forceinline__ Aff aff_compose(const Aff& L, const Aff& E) {
    Aff r;
    r.m00 = L.m00*E.m00 + L.m01*E.m10;
    r.m01 = L.m00*E.m01 + L.m01*E.m11;
    r.m10 = L.m10*E.m00 + L.m11*E.m10;
    r.m11 = L.m10*E.m01 + L.m11*E.m11;
    r.v0  = L.m00*E.v0  + L.m01*E.v1 + L.v0;
    r.v1  = L.m10*E.v0  + L.m11*E.v1 + L.v1;
    return r;
}

__device__ __forceinline__ Aff aff_identity() {
    Aff r; r.m00 = 1.f; r.m01 = 0.f; r.m10 = 0.f; r.m11 = 1.f; r.v0 = 0.f; r.v1 = 0.f;
    return r;
}

// STEP_MAP uses locals a[], d[] and the cd/i constants of the enclosing scope.
#define STEP_MAP(i, S)                                                  \
    {                                                                   \
        const float4 x4 = a[i];                                         \
        const float dyx = ((i)&1) ? d[(i)>>1].z : d[(i)>>1].x;          \
        const float dyy = ((i)&1) ? d[(i)>>1].w : d[(i)>>1].y;          \
        (S).m00 = i00 - (x4.x*cd00 + x4.y*cd10);                        \
        (S).m01 = i01 - (x4.x*cd01 + x4.y*cd11);                        \
        (S).m10 = i10 - (x4.z*cd00 + x4.w*cd10);                        \
        (S).m11 = i11 - (x4.z*cd01 + x4.w*cd11);                        \
        (S).v0  = x4.x*dyx + x4.y*dyy;                                  \
        (S).v1  = x4.z*dyx + x4.w*dyy;                                  \
    }

__global__ __launch_bounds__(NT, 4) void grm_fused(
    const float* __restrict__ xic, const float* __restrict__ dy,
    const float* __restrict__ Aptr, const float* __restrict__ Cptr,
    float4* __restrict__ out4)
{
    // 8 waves x 128 float4 (2 KiB) = 16 KiB. Each wave uses ONLY its slice
    // except the header exchange (barrier-guarded). Slice reuse across
    // phases/chunks is same-wave DS traffic (ordered) or barrier-separated.
    __shared__ float4 lds4[NW * SLICE_F4];

    const int b    = blockIdx.x;
    const int tid  = threadIdx.x;
    const int lane = tid & 63;
    const int wave = tid >> 6;

    float4* slice = lds4 + wave * SLICE_F4;

    const float DT = 1e-3f;
    const float cd00 = Cptr[0]*DT, cd01 = Cptr[1]*DT;
    const float cd10 = Cptr[2]*DT, cd11 = Cptr[3]*DT;
    const float i00 = 1.0f + Aptr[0]*DT, i01 = Aptr[1]*DT;
    const float i10 = Aptr[2]*DT,        i11 = 1.0f + Aptr[3]*DT;

    // Running state entering the current chunk (x at step c*4096). All
    // threads hold the same value; updated uniformly per chunk.
    float xc0 = 1.0f, xc1 = 0.0f;

    for (int c = 0; c < NCH; ++c) {
        // global bases in float4 units; wave covers 512 steps of this chunk
        const int wbase = b * T_ + c * (NT * LPT) + wave * 512;
        const float4* xw = (const float4*)xic + wbase;          // 512 f4
        const float4* dw = (const float4*)dy  + (wbase >> 1);   // 256 f4
        float4*       ow = out4 + (wbase >> 1);                 // 256 f4

        // ---- issue this chunk's global loads, fully coalesced ----
        float4 t[8], u[4];
        #pragma unroll
        for (int j = 0; j < 8; ++j) t[j] = xw[j*64 + lane];
        #pragma unroll
        for (int j = 0; j < 4; ++j) u[j] = dw[j*64 + lane];

        // ---- xic transpose: four owner-rounds through the 2 KiB slice ----
        // Round r covers f in [128r,128r+128); owner o=f>>3, rel=o&15,
        // slot=lane&7, swizzled addr = rel*8 + (slot^(rel&7)). Writes
        // conflict-free; reads 2-way max (free). Same-wave DS ordering
        // makes cross-round slice reuse safe without barriers.
        float4 a[LPT];
        #pragma unroll
        for (int r = 0; r < 4; ++r) {
            #pragma unroll
            for (int jj = 0; jj < 2; ++jj) {
                int j = 2*r + jj;
                int f = j*64 + lane;
                int rel = (f >> 3) & 15;
                slice[rel*8 + ((lane & 7) ^ (rel & 7))] = t[j];
            }
            if ((lane >> 4) == r) {
                int rel = lane & 15;
                #pragma unroll
                for (int s = 0; s < LPT; ++s)
                    a[s] = slice[rel*8 + (s ^ (rel & 7))];
            }
        }

        // ---- dy transpose: two owner-rounds. o=f>>2, rel=o&31, slot=f&3 ----
        float4 d[4];
        #pragma unroll
        for (int r = 0; r < 2; ++r) {
            #pragma unroll
            for (int jj = 0; jj < 2; ++jj) {
                int j = 2*r + jj;
                int f = j*64 + lane;
                int rel = (f >> 2) & 31;
                slice[rel*4 + ((lane & 3) ^ (rel & 3))] = u[j];
            }
            if ((lane >> 5) == r) {
                int rel = lane & 31;
                #pragma unroll
                for (int s = 0; s < 4; ++s)
                    d[s] = slice[rel*4 + (s ^ (rel & 3))];
            }
        }

        // ---- thread-local compose: P = T7 o ... o T0 ----
        Aff P;
        STEP_MAP(0, P);
        #pragma unroll
        for (int i = 1; i < LPT; ++i) { Aff s; STEP_MAP(i, s); P = aff_compose(s, P); }

        // ---- wave Kogge-Stone inclusive scan (64 lanes) ----
        Aff S = P;
        #pragma unroll
        for (int sh = 1; sh < 64; sh <<= 1) {
            Aff q;
            q.m00 = __shfl_up(S.m00, sh); q.m01 = __shfl_up(S.m01, sh);
            q.m10 = __shfl_up(S.m10, sh); q.m11 = __shfl_up(S.m11, sh);
            q.v0  = __shfl_up(S.v0,  sh); q.v1  = __shfl_up(S.v1,  sh);
            if (lane >= sh) S = aff_compose(S, q);
        }

        // ---- wave totals -> own slice header (slice free: a,d in regs) ----
        if (lane == 63) {
            float* h = (float*)slice;
            h[0] = S.m00; h[1] = S.m01; h[2] = S.m10; h[3] = S.m11;
            h[4] = S.v0;  h[5] = S.v1;
        }
        __syncthreads();

        // ---- wave-exclusive prefix AND chunk total over all 8 headers ----
        Aff Ew;             // compose of waves [0, wave)
        Aff Acc = aff_identity();
        #pragma unroll
        for (int w = 0; w < NW; ++w) {
            if (w == wave) Ew = Acc;
            const float* h = (const float*)(lds4 + w * SLICE_F4);
            Aff t2;
            t2.m00 = h[0]; t2.m01 = h[1]; t2.m10 = h[2]; t2.m11 = h[3];
            t2.v0  = h[4]; t2.v1  = h[5];
            Acc = aff_compose(t2, Acc);
        }
        __syncthreads();   // headers consumed; slices reusable for out staging

        // ---- lane-exclusive prefix within wave ----
        Aff El;
        El.m00 = __shfl_up(S.m00, 1); El.m01 = __shfl_up(S.m01, 1);
        El.m10 = __shfl_up(S.m10, 1); El.m11 = __shfl_up(S.m11, 1);
        El.v0  = __shfl_up(S.v0,  1); El.v1  = __shfl_up(S.v1,  1);
        if (lane == 0) El = aff_identity();

        Aff E = aff_compose(El, Ew);
        // thread's entering state = E applied to the chunk-entering state
        float x0 = E.m00*xc0 + E.m01*xc1 + E.v0;
        float x1 = E.m10*xc0 + E.m11*xc1 + E.v1;
        // advance the chunk carry through this chunk's total (uniform)
        {
            float n0 = Acc.m00*xc0 + Acc.m01*xc1 + Acc.v0;
            float n1 = Acc.m10*xc0 + Acc.m11*xc1 + Acc.v1;
            xc0 = n0; xc1 = n1;
        }

        // ---- replay from registers ----
        float4 o4[4];
        #pragma unroll
        for (int i = 0; i < LPT; ++i) {
            float oxx = cd00*x0 + cd01*x1;
            float oyy = cd10*x0 + cd11*x1;
            if (i & 1) { o4[i>>1].z = oxx; o4[i>>1].w = oyy; }
            else       { o4[i>>1].x = oxx; o4[i>>1].y = oyy; }
            Aff s; STEP_MAP(i, s);
            float nx0 = s.m00*x0 + s.m01*x1 + s.v0;
            float nx1 = s.m10*x0 + s.m11*x1 + s.v1;
            x0 = nx0; x1 = nx1;
        }

        // ---- out transpose: own-order -> coalesced stores, two rounds ----
        #pragma unroll
        for (int r = 0; r < 2; ++r) {
            if ((lane >> 5) == r) {
                int rel = lane & 31;
                #pragma unroll
                for (int s = 0; s < 4; ++s)
                    slice[rel*4 + (s ^ (rel & 3))] = o4[s];
            }
            #pragma unroll
            for (int jj = 0; jj < 2; ++jj) {
                int j = 2*r + jj;
                int f = j*64 + lane;
                int rel = (f >> 2) & 31;
                ow[f] = slice[rel*4 + ((lane & 3) ^ (rel & 3))];
            }
        }
        // next chunk's transposes write this wave's own slice again --
        // same-wave DS ordering after the stores above makes that safe.
    }
}

#undef STEP_MAP

extern "C" void kernel_launch(void* const* d_in, const int* in_sizes, int n_in,
                              void* d_out, int out_size, void* d_ws, size_t ws_size,
                              hipStream_t stream) {
    const float* xic  = (const float*)d_in[0];   // [B,T,2,2]
    const float* dy   = (const float*)d_in[1];   // [B,T,2]
    const float* Aptr = (const float*)d_in[2];   // [2,2]
    const float* Cptr = (const float*)d_in[3];   // [2,2]
    float4* out = (float4*)d_out;                // [B,T,2]

    grm_fused<<<B_, NT, 0, stream>>>(xic, dy, Aptr, Cptr, out);
}

// Round 9
// 160.025 us; speedup vs baseline: 1.1286x; 1.1064x over previous
//
#include <hip/hip_runtime.h>

// GaussianRecuModel: B=512 batches, T=8192-step affine recurrence on 2-state x.
//   x_{t+1} = Mt x_t + bt,  Mt = I + dt*A - dt*(xic_t C),  bt = xic_t dy_t
//   out_t   = dt * C x_t   (state BEFORE update)
//
// R4:    wave-coalesced float4 global access; XOR-swizzled per-wave LDS slice
//        transposes coalesced order <-> 8-contiguous-steps-per-thread order.
// R5-R10: 1024-thr monolith dead end (1 block/CU, 64-VGPR hard cap, all
//        pipeline attempts spilled: WRITE_SIZE 32->49->79->97 MB).
// R11:   512-thr blocks, 2 chunks/batch. Right structure, but the added
//        register state (unrolled Ew+Acc header loop, loop-carried xc)
//        pushed the 52-reg base flow past the 64 cap -> spill again (78 MB).
// R12:   R11 geometry, R6 register profile. (a) header loop back to the
//        runtime `w<wave` form (Ew only, no Acc); (b) chunk carry passed
//        through a dedicated LDS slot, written by the last thread after its
//        replay (it ends holding the chunk-final state), read by all after
//        the next chunk's first barrier -- race-free by barrier separation;
//        (c) #pragma unroll 1 on the chunk loop so the body's allocation
//        problem is exactly R6's proven 52-VGPR single body.

#define B_   512
#define T_   8192
#define LPT  8                   // steps per thread per chunk
#define NT   512                 // threads per block (8 waves)
#define NW   (NT / 64)           // waves per block
#define NCH  2                   // chunks per batch
static_assert(NT * LPT * NCH == T_, "chunks cover one batch");

#define SLICE_F4 128             // 2 KiB work slice per wave

struct Aff { float m00, m01, m10, m11, v0, v1; };

__device__ __forceinline__ Aff aff_compose(const Aff& L, const Aff& E) {
    Aff r;
    r.m00 = L.m00*E.m00 + L.m01*E.m10;
    r.m01 = L.m00*E.m01 + L.m01*E.m11;
    r.m10 = L.m10*E.m00 + L.m11*E.m10;
    r.m11 = L.m10*E.m01 + L.m11*E.m11;
    r.v0  = L.m00*E.v0  + L.m01*E.v1 + L.v0;
    r.v1  = L.m10*E.v0  + L.m11*E.v1 + L.v1;
    return r;
}

__device__ __forceinline__ Aff aff_identity() {
    Aff r; r.m00 = 1.f; r.m01 = 0.f; r.m10 = 0.f; r.m11 = 1.f; r.v0 = 0.f; r.v1 = 0.f;
    return r;
}

// STEP_MAP uses locals a[], d[] and the cd/i constants of the enclosing scope.
#define STEP_MAP(i, S)                                                  \
    {                                                                   \
        const float4 x4 = a[i];                                         \
        const float dyx = ((i)&1) ? d[(i)>>1].z : d[(i)>>1].x;          \
        const float dyy = ((i)&1) ? d[(i)>>1].w : d[(i)>>1].y;          \
        (S).m00 = i00 - (x4.x*cd00 + x4.y*cd10);                        \
        (S).m01 = i01 - (x4.x*cd01 + x4.y*cd11);                        \
        (S).m10 = i10 - (x4.z*cd00 + x4.w*cd10);                        \
        (S).m11 = i11 - (x4.z*cd01 + x4.w*cd11);                        \
        (S).v0  = x4.x*dyx + x4.y*dyy;                                  \
        (S).v1  = x4.z*dyx + x4.w*dyy;                                  \
    }

__global__ __launch_bounds__(NT, 4) void grm_fused(
    const float* __restrict__ xic, const float* __restrict__ dy,
    const float* __restrict__ Aptr, const float* __restrict__ Cptr,
    float4* __restrict__ out4)
{
    // 8 waves x 128 float4 (2 KiB) = 16 KiB work slices + 1 float4 carry
    // slot. Each wave uses ONLY its slice except the header exchange
    // (barrier-guarded) and the carry slot (single writer, barrier-separated
    // from all reads).
    __shared__ float4 lds4[NW * SLICE_F4 + 1];
    float* carry = (float*)(lds4 + NW * SLICE_F4);

    const int b    = blockIdx.x;
    const int tid  = threadIdx.x;
    const int lane = tid & 63;
    const int wave = tid >> 6;

    float4* slice = lds4 + wave * SLICE_F4;

    const float DT = 1e-3f;
    const float cd00 = Cptr[0]*DT, cd01 = Cptr[1]*DT;
    const float cd10 = Cptr[2]*DT, cd11 = Cptr[3]*DT;
    const float i00 = 1.0f + Aptr[0]*DT, i01 = Aptr[1]*DT;
    const float i10 = Aptr[2]*DT,        i11 = 1.0f + Aptr[3]*DT;

    // initial state x = [1, 0]; first read is after chunk-0's first barrier
    if (tid == 0) { carry[0] = 1.0f; carry[1] = 0.0f; }

    #pragma unroll 1
    for (int c = 0; c < NCH; ++c) {
        // global bases in float4 units; wave covers 512 steps of this chunk
        const int wbase = b * T_ + c * (NT * LPT) + wave * 512;
        const float4* xw = (const float4*)xic + wbase;          // 512 f4
        const float4* dw = (const float4*)dy  + (wbase >> 1);   // 256 f4
        float4*       ow = out4 + (wbase >> 1);                 // 256 f4

        // ---- issue this chunk's global loads, fully coalesced ----
        float4 t[8], u[4];
        #pragma unroll
        for (int j = 0; j < 8; ++j) t[j] = xw[j*64 + lane];
        #pragma unroll
        for (int j = 0; j < 4; ++j) u[j] = dw[j*64 + lane];

        // ---- xic transpose: four owner-rounds through the 2 KiB slice ----
        // Round r covers f in [128r,128r+128); owner o=f>>3, rel=o&15,
        // slot=lane&7, swizzled addr = rel*8 + (slot^(rel&7)). Writes
        // conflict-free; reads 2-way max (free). Same-wave DS ordering
        // makes cross-round slice reuse safe without barriers.
        float4 a[LPT];
        #pragma unroll
        for (int r = 0; r < 4; ++r) {
            #pragma unroll
            for (int jj = 0; jj < 2; ++jj) {
                int j = 2*r + jj;
                int f = j*64 + lane;
                int rel = (f >> 3) & 15;
                slice[rel*8 + ((lane & 7) ^ (rel & 7))] = t[j];
            }
            if ((lane >> 4) == r) {
                int rel = lane & 15;
                #pragma unroll
                for (int s = 0; s < LPT; ++s)
                    a[s] = slice[rel*8 + (s ^ (rel & 7))];
            }
        }

        // ---- dy transpose: two owner-rounds. o=f>>2, rel=o&31, slot=f&3 ----
        float4 d[4];
        #pragma unroll
        for (int r = 0; r < 2; ++r) {
            #pragma unroll
            for (int jj = 0; jj < 2; ++jj) {
                int j = 2*r + jj;
                int f = j*64 + lane;
                int rel = (f >> 2) & 31;
                slice[rel*4 + ((lane & 3) ^ (rel & 3))] = u[j];
            }
            if ((lane >> 5) == r) {
                int rel = lane & 31;
                #pragma unroll
                for (int s = 0; s < 4; ++s)
                    d[s] = slice[rel*4 + (s ^ (rel & 3))];
            }
        }

        // ---- thread-local compose: P = T7 o ... o T0 ----
        Aff P;
        STEP_MAP(0, P);
        #pragma unroll
        for (int i = 1; i < LPT; ++i) { Aff s; STEP_MAP(i, s); P = aff_compose(s, P); }

        // ---- wave Kogge-Stone inclusive scan (64 lanes) ----
        Aff S = P;
        #pragma unroll
        for (int sh = 1; sh < 64; sh <<= 1) {
            Aff q;
            q.m00 = __shfl_up(S.m00, sh); q.m01 = __shfl_up(S.m01, sh);
            q.m10 = __shfl_up(S.m10, sh); q.m11 = __shfl_up(S.m11, sh);
            q.v0  = __shfl_up(S.v0,  sh); q.v1  = __shfl_up(S.v1,  sh);
            if (lane >= sh) S = aff_compose(S, q);
        }

        // ---- wave totals -> own slice header (slice free: a,d in regs) ----
        if (lane == 63) {
            float* h = (float*)slice;
            h[0] = S.m00; h[1] = S.m01; h[2] = S.m10; h[3] = S.m11;
            h[4] = S.v0;  h[5] = S.v1;
        }
        __syncthreads();                       // B1

        // chunk-entering state (uniform; written last chunk or at init)
        const float xc0 = carry[0], xc1 = carry[1];

        // ---- wave-exclusive prefix (runtime loop, Ew only -- R6 form) ----
        Aff Ew = aff_identity();
        for (int w = 0; w < wave; ++w) {
            const float* h = (const float*)(lds4 + w * SLICE_F4);
            Aff t2;
            t2.m00 = h[0]; t2.m01 = h[1]; t2.m10 = h[2]; t2.m11 = h[3];
            t2.v0  = h[4]; t2.v1  = h[5];
            Ew = aff_compose(t2, Ew);
        }
        __syncthreads();                       // B2: headers consumed

        // ---- lane-exclusive prefix within wave ----
        Aff El;
        El.m00 = __shfl_up(S.m00, 1); El.m01 = __shfl_up(S.m01, 1);
        El.m10 = __shfl_up(S.m10, 1); El.m11 = __shfl_up(S.m11, 1);
        El.v0  = __shfl_up(S.v0,  1); El.v1  = __shfl_up(S.v1,  1);
        if (lane == 0) El = aff_identity();

        Aff E = aff_compose(El, Ew);
        // thread's entering state = E applied to the chunk-entering state
        float x0 = E.m00*xc0 + E.m01*xc1 + E.v0;
        float x1 = E.m10*xc0 + E.m11*xc1 + E.v1;

        // ---- replay from registers ----
        float4 o4[4];
        #pragma unroll
        for (int i = 0; i < LPT; ++i) {
            float oxx = cd00*x0 + cd01*x1;
            float oyy = cd10*x0 + cd11*x1;
            if (i & 1) { o4[i>>1].z = oxx; o4[i>>1].w = oyy; }
            else       { o4[i>>1].x = oxx; o4[i>>1].y = oyy; }
            Aff s; STEP_MAP(i, s);
            float nx0 = s.m00*x0 + s.m01*x1 + s.v0;
            float nx1 = s.m10*x0 + s.m11*x1 + s.v1;
            x0 = nx0; x1 = nx1;
        }

        // ---- last thread now holds the chunk-final state: publish carry.
        // Write is after B2 of this chunk; all reads of this slot are after
        // B1 of the next chunk -> race-free.
        if (wave == NW-1 && lane == 63) { carry[0] = x0; carry[1] = x1; }

        // ---- out transpose: own-order -> coalesced stores, two rounds ----
        #pragma unroll
        for (int r = 0; r < 2; ++r) {
            if ((lane >> 5) == r) {
                int rel = lane & 31;
                #pragma unroll
                for (int s = 0; s < 4; ++s)
                    slice[rel*4 + (s ^ (rel & 3))] = o4[s];
            }
            #pragma unroll
            for (int jj = 0; jj < 2; ++jj) {
                int j = 2*r + jj;
                int f = j*64 + lane;
                int rel = (f >> 2) & 31;
                ow[f] = slice[rel*4 + ((lane & 3) ^ (rel & 3))];
            }
        }
        // next chunk's transposes rewrite this wave's own slice -- same-wave
        // DS ordering after the reads above makes that safe.
    }
}

#undef STEP_MAP

extern "C" void kernel_launch(void* const* d_in, const int* in_sizes, int n_in,
                              void* d_out, int out_size, void* d_ws, size_t ws_size,
                              hipStream_t stream) {
    const float* xic  = (const float*)d_in[0];   // [B,T,2,2]
    const float* dy   = (const float*)d_in[1];   // [B,T,2]
    const float* Aptr = (const float*)d_in[2];   // [2,2]
    const float* Cptr = (const float*)d_in[3];   // [2,2]
    float4* out = (float4*)d_out;                // [B,T,2]

    grm_fused<<<B_, NT, 0, stream>>>(xic, dy, Aptr, Cptr, out);
}